// Round 3
// baseline (4467.433 us; speedup 1.0000x reference)
//
#include <hip/hip_runtime.h>
#include <hip/hip_bf16.h>

typedef __hip_bfloat16 bf16;

#define U_N   100000
#define B_N   50000
#define N_TOT 150000
#define NE_UB 800000
#define NE_BB 600000
#define NP    400000
#define DU    64
#define DB    128
#define HD    128

__device__ __forceinline__ float b2f(bf16 v) { return __bfloat162float(v); }

// compile-time typed load of "float tensor input" that may be f32 or bf16
template<bool F32>
__device__ __forceinline__ float ldf(const void* p, size_t i) {
    if (F32) return ((const float*)p)[i];
    return b2f(((const bf16*)p)[i]);
}

// Detect input dtype: bits 7..14 of each 32-bit word = bf16 exponent of the
// LOWER half. True bf16 N(0,1) data: exponent <= ~130 always -> count == 0.
// f32 data: those are random mantissa bits -> ~47% of words exceed 134.
__global__ void k_sniff(const unsigned int* __restrict__ w, int* __restrict__ flag) {
    __shared__ int cnt;
    if (threadIdx.x == 0) cnt = 0;
    __syncthreads();
    int local = 0;
    for (int i = threadIdx.x; i < 4096; i += 256) {
        unsigned e = (w[i] >> 7) & 0xffu;
        if (e > 134u) local++;
    }
    atomicAdd(&cnt, local);
    __syncthreads();
    if (threadIdx.x == 0) flag[0] = (cnt > 100) ? 1 : 0;   // 1 = f32 inputs
}

// out[r, c] = sum_k x[r,k] * W[k,c] + bias[c]   (8 rows per 128-thread block)
template<int K, bool F32>
__global__ void k_init_gemm(const int* __restrict__ dflag,
                            const void* __restrict__ x, const void* __restrict__ W,
                            const void* __restrict__ bias, float* __restrict__ out,
                            int nrows) {
    if ((dflag[0] != 0) != F32) return;
    __shared__ float row[8][K];
    const int c  = threadIdx.x;           // 0..127 output column
    const int r0 = blockIdx.x * 8;
    for (int i = threadIdx.x; i < 8 * K; i += 128) {
        int rr = i / K, kk = i % K;
        int r = r0 + rr;
        row[rr][kk] = (r < nrows) ? ldf<F32>(x, (size_t)r * K + kk) : 0.0f;
    }
    __syncthreads();
    float acc[8];
#pragma unroll
    for (int i = 0; i < 8; i++) acc[i] = 0.0f;
    for (int k = 0; k < K; k++) {
        float w = ldf<F32>(W, k * HD + c);
#pragma unroll
        for (int i = 0; i < 8; i++) acc[i] = fmaf(row[i][k], w, acc[i]);
    }
    float bv = ldf<F32>(bias, c);
#pragma unroll
    for (int i = 0; i < 8; i++) {
        int r = r0 + i;
        if (r < nrows) out[(size_t)r * HD + c] = acc[i] + bv;
    }
}

__global__ void k_deg(const int* __restrict__ us, const int* __restrict__ ud,
                      float* __restrict__ deg) {
    int e = blockIdx.x * blockDim.x + threadIdx.x;
    if (e < NE_UB) {
        atomicAdd(&deg[us[e]], 1.0f);
        atomicAdd(&deg[U_N + ud[e]], 1.0f);
    }
}

__global__ void k_degb(const int* __restrict__ bd, float* __restrict__ degb) {
    int e = blockIdx.x * blockDim.x + threadIdx.x;
    if (e < NE_BB) atomicAdd(&degb[bd[e]], 1.0f);
}

__global__ void k_dinv(float* __restrict__ dinv) {
    int i = blockIdx.x * blockDim.x + threadIdx.x;
    if (i < N_TOT) {
        float d = dinv[i];
        dinv[i] = (d > 0.0f) ? 1.0f / sqrtf(d) : 0.0f;
    }
}

// one wave per undirected ub edge; lane handles 2 features (float2); both directions
__global__ void k_prop(const int* __restrict__ us, const int* __restrict__ ud,
                       const float* __restrict__ dinv,
                       const float* __restrict__ xin, float* __restrict__ xout) {
    int wid  = (blockIdx.x * blockDim.x + threadIdx.x) >> 6;
    int lane = threadIdx.x & 63;
    if (wid >= NE_UB) return;
    int u = us[wid];
    int b = U_N + ud[wid];
    float nrm = dinv[u] * dinv[b];
    float2 vu = ((const float2*)(xin + (size_t)u * HD))[lane];
    float2 vb = ((const float2*)(xin + (size_t)b * HD))[lane];
    float* ou = xout + (size_t)u * HD + 2 * lane;
    float* ob = xout + (size_t)b * HD + 2 * lane;
    atomicAdd(ob + 0, vu.x * nrm);
    atomicAdd(ob + 1, vu.y * nrm);
    atomicAdd(ou + 0, vb.x * nrm);
    atomicAdd(ou + 1, vb.y * nrm);
}

// acc = (acc + s) * scale
__global__ void k_add_scale(float* __restrict__ acc, const float* __restrict__ s,
                            float scale, int n4) {
    int i = blockIdx.x * blockDim.x + threadIdx.x;
    if (i < n4) {
        float4 a = ((float4*)acc)[i];
        float4 b = ((const float4*)s)[i];
        a.x = (a.x + b.x) * scale;
        a.y = (a.y + b.y) * scale;
        a.z = (a.z + b.z) * scale;
        a.w = (a.w + b.w) * scale;
        ((float4*)acc)[i] = a;
    }
}

// one wave per bb edge; scatter h[src] into agg[dst]
__global__ void k_bbscat(const int* __restrict__ bs, const int* __restrict__ bd,
                         const float* __restrict__ h, float* __restrict__ agg) {
    int wid  = (blockIdx.x * blockDim.x + threadIdx.x) >> 6;
    int lane = threadIdx.x & 63;
    if (wid >= NE_BB) return;
    int s = bs[wid];
    int d = bd[wid];
    float2 v = ((const float2*)(h + (size_t)s * HD))[lane];
    float* o = agg + (size_t)d * HD + 2 * lane;
    atomicAdd(o + 0, v.x);
    atomicAdd(o + 1, v.y);
}

// hout[r,c] = relu( (agg[r]/max(degb,1)) @ Wl + bl + h[r] @ Wr )
template<bool F32>
__global__ void k_glayer(const int* __restrict__ dflag,
                         const float* __restrict__ agg, const float* __restrict__ degb,
                         const float* __restrict__ h,
                         const void* __restrict__ Wl, const void* __restrict__ bl,
                         const void* __restrict__ Wr, float* __restrict__ hout) {
    if ((dflag[0] != 0) != F32) return;
    __shared__ float sa[8][HD];
    __shared__ float sh[8][HD];
    const int c  = threadIdx.x;
    const int r0 = blockIdx.x * 8;
#pragma unroll
    for (int i = 0; i < 8; i++) {
        int r = r0 + i;
        if (r < B_N) {
            float dsc = 1.0f / fmaxf(degb[r], 1.0f);
            sa[i][c] = agg[(size_t)r * HD + c] * dsc;
            sh[i][c] = h[(size_t)r * HD + c];
        } else {
            sa[i][c] = 0.0f;
            sh[i][c] = 0.0f;
        }
    }
    __syncthreads();
    float acc[8];
#pragma unroll
    for (int i = 0; i < 8; i++) acc[i] = 0.0f;
    for (int k = 0; k < HD; k++) {
        float wl = ldf<F32>(Wl, k * HD + c);
        float wr = ldf<F32>(Wr, k * HD + c);
#pragma unroll
        for (int i = 0; i < 8; i++) {
            acc[i] = fmaf(sa[i][k], wl, acc[i]);
            acc[i] = fmaf(sh[i][k], wr, acc[i]);
        }
    }
    float bv = ldf<F32>(bl, c);
#pragma unroll
    for (int i = 0; i < 8; i++) {
        int r = r0 + i;
        if (r < B_N) hout[(size_t)r * HD + c] = fmaxf(acc[i] + bv, 0.0f);
    }
}

// attention fusion head, 4 rows per 128-thread block (2 waves)
template<bool F32>
__global__ void k_fuse(const int* __restrict__ dflag,
                       const float* __restrict__ collab, const float* __restrict__ content,
                       const void* __restrict__ Wf1, const void* __restrict__ bf1v,
                       const void* __restrict__ Wf2, const void* __restrict__ bf2v,
                       float* __restrict__ fused) {
    if ((dflag[0] != 0) != F32) return;
    const int R = 4;
    __shared__ float sc[R][HD];
    __shared__ float sh[R][HD];
    __shared__ float part[2][R][2];
    __shared__ float attn[R][2];
    const int c  = threadIdx.x;
    const int r0 = blockIdx.x * R;
#pragma unroll
    for (int i = 0; i < R; i++) {
        int r = r0 + i;
        sc[i][c] = (r < B_N) ? collab[(size_t)r * HD + c] : 0.0f;
        sh[i][c] = (r < B_N) ? content[(size_t)r * HD + c] : 0.0f;
    }
    __syncthreads();
    float t[R];
#pragma unroll
    for (int i = 0; i < R; i++) t[i] = 0.0f;
    for (int k = 0; k < HD; k++) {
        float w = ldf<F32>(Wf1, k * HD + c);
#pragma unroll
        for (int i = 0; i < R; i++) t[i] = fmaf(sc[i][k], w, t[i]);
    }
    for (int k = 0; k < HD; k++) {
        float w = ldf<F32>(Wf1, (size_t)(HD + k) * HD + c);
#pragma unroll
        for (int i = 0; i < R; i++) t[i] = fmaf(sh[i][k], w, t[i]);
    }
    float b1  = ldf<F32>(bf1v, c);
    float w20 = ldf<F32>(Wf2, c * 2 + 0);
    float w21 = ldf<F32>(Wf2, c * 2 + 1);
    float p0[R], p1[R];
#pragma unroll
    for (int i = 0; i < R; i++) {
        float tv = fmaxf(t[i] + b1, 0.0f);
        p0[i] = tv * w20;
        p1[i] = tv * w21;
    }
#pragma unroll
    for (int i = 0; i < R; i++) {
        for (int off = 32; off > 0; off >>= 1) {
            p0[i] += __shfl_down(p0[i], off, 64);
            p1[i] += __shfl_down(p1[i], off, 64);
        }
    }
    int wv   = threadIdx.x >> 6;
    int lane = threadIdx.x & 63;
    if (lane == 0) {
#pragma unroll
        for (int i = 0; i < R; i++) { part[wv][i][0] = p0[i]; part[wv][i][1] = p1[i]; }
    }
    __syncthreads();
    if (threadIdx.x < R) {
        int i = threadIdx.x;
        float s0 = part[0][i][0] + part[1][i][0] + ldf<F32>(bf2v, 0);
        float s1 = part[0][i][1] + part[1][i][1] + ldf<F32>(bf2v, 1);
        float m  = fmaxf(s0, s1);
        float e0 = expf(s0 - m), e1 = expf(s1 - m);
        float inv = 1.0f / (e0 + e1);
        attn[i][0] = e0 * inv;
        attn[i][1] = e1 * inv;
    }
    __syncthreads();
#pragma unroll
    for (int i = 0; i < R; i++) {
        int r = r0 + i;
        if (r < B_N)
            fused[(size_t)r * HD + c] = attn[i][0] * sc[i][c] + attn[i][1] * sh[i][c];
    }
}

// one wave per prediction: dot(user_emb[pu], fused[pb]) over 128 dims
template<bool F32>
__global__ void k_score(const int* __restrict__ dflag,
                        const int* __restrict__ pu, const int* __restrict__ pb,
                        const float* __restrict__ uemb, const float* __restrict__ fused,
                        void* __restrict__ out) {
    if ((dflag[0] != 0) != F32) return;
    int wid  = (blockIdx.x * blockDim.x + threadIdx.x) >> 6;
    int lane = threadIdx.x & 63;
    if (wid >= NP) return;
    int u = pu[wid];
    int b = pb[wid];
    float2 a = ((const float2*)(uemb + (size_t)u * HD))[lane];
    float2 f = ((const float2*)(fused + (size_t)b * HD))[lane];
    float s = a.x * f.x + a.y * f.y;
    for (int off = 32; off > 0; off >>= 1) s += __shfl_down(s, off, 64);
    if (lane == 0) {
        if (F32) ((float*)out)[wid] = s;
        else     ((bf16*)out)[wid]  = __float2bfloat16(s);
    }
}

extern "C" void kernel_launch(void* const* d_in, const int* in_sizes, int n_in,
                              void* d_out, int out_size, void* d_ws, size_t ws_size,
                              hipStream_t stream) {
    const void* user_x = d_in[0];
    const void* book_x = d_in[1];
    const int*  ub_src = (const int*)d_in[2];
    const int*  ub_dst = (const int*)d_in[3];
    const int*  bb_src = (const int*)d_in[4];
    const int*  bb_dst = (const int*)d_in[5];
    const int*  pred_u = (const int*)d_in[6];
    const int*  pred_b = (const int*)d_in[7];
    const void* Wu   = d_in[8];
    const void* bu   = d_in[9];
    const void* Wub  = d_in[10];
    const void* bub  = d_in[11];
    const void* Wbb  = d_in[12];
    const void* bbb  = d_in[13];
    const void* Wl1  = d_in[14];
    const void* bl1  = d_in[15];
    const void* Wr1  = d_in[16];
    const void* Wl2  = d_in[17];
    const void* bl2  = d_in[18];
    const void* Wr2  = d_in[19];
    const void* Wf1  = d_in[20];
    const void* bf1v = d_in[21];
    const void* Wf2  = d_in[22];
    const void* bf2v = d_in[23];

    // ---- workspace layout: 200064 + 2*N*H floats = 154.4 MB ----
    float* ws   = (float*)d_ws;
    const size_t NH = (size_t)N_TOT * HD;        // 19.2M floats
    const size_t need = (200064 + 2 * NH) * sizeof(float);
    if (ws_size < need) return;  // diagnostic: absmax would be exactly max|ref|

    float* dinv  = ws;                           // [0, 150000)
    float* degb  = ws + N_TOT;                   // [150000, 200000)
    int*   dflag = (int*)(ws + 200000);          // dtype flag
    float* ACC   = ws + 200064;                  // N*H: x0 -> x0+x2 -> xf
    float* XBUF  = ACC + NH;                     // N*H: x1; later content tiles
    float* hA    = XBUF;                         // B*H
    float* agg   = XBUF + (size_t)B_N * HD;      // B*H
    float* hB    = XBUF + 2 * (size_t)B_N * HD;  // B*H (3*B*H == N*H)
    float* fused = agg;                          // reuse agg after layer 2

    // zero aux + x1 buffer (ws is poisoned 0xAA each launch)
    hipMemsetAsync(ws, 0, 200064 * sizeof(float), stream);
    hipMemsetAsync(XBUF, 0, NH * sizeof(float), stream);

    // dtype sniff (writes dflag; must precede all templated kernels)
    k_sniff<<<1, 256, 0, stream>>>((const unsigned int*)user_x, dflag);

#define DUAL(kern, grid, blk, ...) \
    kern<false><<<grid, blk, 0, stream>>>(dflag, __VA_ARGS__); \
    kern<true ><<<grid, blk, 0, stream>>>(dflag, __VA_ARGS__);
#define DUALK(kern, K, grid, blk, ...) \
    kern<K, false><<<grid, blk, 0, stream>>>(dflag, __VA_ARGS__); \
    kern<K, true ><<<grid, blk, 0, stream>>>(dflag, __VA_ARGS__);

    // x0 = [user_x@Wu+bu ; book_x@Wub+bub] -> ACC
    DUALK(k_init_gemm, DU, (U_N + 7) / 8, 128, user_x, Wu, bu, ACC, U_N);
    DUALK(k_init_gemm, DB, (B_N + 7) / 8, 128, book_x, Wub, bub,
          ACC + (size_t)U_N * HD, B_N);

    // degrees & symmetric norm
    k_deg<<<(NE_UB + 255) / 256, 256, 0, stream>>>(ub_src, ub_dst, dinv);
    k_degb<<<(NE_BB + 255) / 256, 256, 0, stream>>>(bb_dst, degb);
    k_dinv<<<(N_TOT + 255) / 256, 256, 0, stream>>>(dinv);

    // round 1: x1 = prop(x0) -> XBUF (zeroed)
    k_prop<<<NE_UB / 4, 256, 0, stream>>>(ub_src, ub_dst, dinv, ACC, XBUF);
    // round 2: scatter x2 = prop(x1) directly onto ACC (holds x0)
    k_prop<<<NE_UB / 4, 256, 0, stream>>>(ub_src, ub_dst, dinv, XBUF, ACC);
    // xf = (x0 + x2 + x1)/3
    const int n4 = (int)(NH / 4);
    k_add_scale<<<(n4 + 255) / 256, 256, 0, stream>>>(ACC, XBUF, 1.0f / 3.0f, n4);

    // content network: h = book_x@Wbb+bbb -> hA (x1 fully consumed above)
    DUALK(k_init_gemm, DB, (B_N + 7) / 8, 128, book_x, Wbb, bbb, hA, B_N);
    // layer 1
    hipMemsetAsync(agg, 0, (size_t)B_N * HD * sizeof(float), stream);
    k_bbscat<<<NE_BB / 4, 256, 0, stream>>>(bb_src, bb_dst, hA, agg);
    DUAL(k_glayer, (B_N + 7) / 8, 128, agg, degb, hA, Wl1, bl1, Wr1, hB);
    // layer 2 (output overwrites hA, which is dead)
    hipMemsetAsync(agg, 0, (size_t)B_N * HD * sizeof(float), stream);
    k_bbscat<<<NE_BB / 4, 256, 0, stream>>>(bb_src, bb_dst, hB, agg);
    DUAL(k_glayer, (B_N + 7) / 8, 128, agg, degb, hB, Wl2, bl2, Wr2, hA);

    // attention fusion: collab = ACC[U:], content = hA -> fused (reuses agg)
    DUAL(k_fuse, (B_N + 3) / 4, 128, ACC + (size_t)U_N * HD, hA,
         Wf1, bf1v, Wf2, bf2v, fused);
    // scores
    DUAL(k_score, NP / 4, 256, pred_u, pred_b, ACC, fused, d_out);

#undef DUAL
#undef DUALK
}

// Round 7
// 1294.935 us; speedup vs baseline: 3.4499x; 3.4499x over previous
//
#include <hip/hip_runtime.h>
#include <hip/hip_bf16.h>

#define U_N   100000
#define B_N   50000
#define N_TOT 150000
#define NE_UB 800000
#define NE_BB 600000
#define NP    400000
#define DU    64
#define DB    128
#define HD    128

// ---------------- dense blocks (all f32) ----------------

// out[r, c] = sum_k x[r,k] * W[k,c] + bias[c]   (8 rows per 128-thread block)
template<int K>
__global__ void k_init_gemm(const float* __restrict__ x, const float* __restrict__ W,
                            const float* __restrict__ bias, float* __restrict__ out,
                            int nrows) {
    __shared__ float row[8][K];
    const int c  = threadIdx.x;
    const int r0 = blockIdx.x * 8;
    for (int i = threadIdx.x; i < 8 * K; i += 128) {
        int rr = i / K, kk = i % K;
        int r = r0 + rr;
        row[rr][kk] = (r < nrows) ? x[(size_t)r * K + kk] : 0.0f;
    }
    __syncthreads();
    float acc[8];
#pragma unroll
    for (int i = 0; i < 8; i++) acc[i] = 0.0f;
    for (int k = 0; k < K; k++) {
        float w = W[k * HD + c];
#pragma unroll
        for (int i = 0; i < 8; i++) acc[i] = fmaf(row[i][k], w, acc[i]);
    }
    float bv = bias[c];
#pragma unroll
    for (int i = 0; i < 8; i++) {
        int r = r0 + i;
        if (r < nrows) out[(size_t)r * HD + c] = acc[i] + bv;
    }
}

// ---------------- CSR build: count -> scan -> fill ----------------

__global__ void k_cnt_ub(const int* __restrict__ us, const int* __restrict__ ud,
                         int* __restrict__ cnt) {
    int e = blockIdx.x * blockDim.x + threadIdx.x;
    if (e < NE_UB) {
        atomicAdd(&cnt[us[e]], 1);
        atomicAdd(&cnt[U_N + ud[e]], 1);
    }
}

__global__ void k_cnt_bb(const int* __restrict__ bd, int* __restrict__ cnt) {
    int e = blockIdx.x * blockDim.x + threadIdx.x;
    if (e < NE_BB) atomicAdd(&cnt[bd[e]], 1);
}

__global__ void k_dinv(const int* __restrict__ cnt, float* __restrict__ dinv) {
    int i = blockIdx.x * blockDim.x + threadIdx.x;
    if (i < N_TOT) {
        int d = cnt[i];
        dinv[i] = (d > 0) ? 1.0f / sqrtf((float)d) : 0.0f;
    }
}

// hierarchical exclusive scan: 1024 elems / block (256 thr x 4)
__global__ void k_scan1(const int* __restrict__ cnt, int* __restrict__ rs,
                        int* __restrict__ bsum, int n) {
    __shared__ int ts[256];
    const int t = threadIdx.x;
    const int base = blockIdx.x * 1024 + t * 4;
    int v0 = (base + 0 < n) ? cnt[base + 0] : 0;
    int v1 = (base + 1 < n) ? cnt[base + 1] : 0;
    int v2 = (base + 2 < n) ? cnt[base + 2] : 0;
    int v3 = (base + 3 < n) ? cnt[base + 3] : 0;
    int local = v0 + v1 + v2 + v3;
    ts[t] = local;
    __syncthreads();
    for (int off = 1; off < 256; off <<= 1) {
        int x = (t >= off) ? ts[t - off] : 0;
        __syncthreads();
        ts[t] += x;
        __syncthreads();
    }
    int ex = ts[t] - local;
    if (base + 0 < n) rs[base + 0] = ex;
    if (base + 1 < n) rs[base + 1] = ex + v0;
    if (base + 2 < n) rs[base + 2] = ex + v0 + v1;
    if (base + 3 < n) rs[base + 3] = ex + v0 + v1 + v2;
    if (t == 0) bsum[blockIdx.x] = ts[255];
}

__global__ void k_scan2(int* __restrict__ bsum, int nb) {
    __shared__ int ts[256];
    const int t = threadIdx.x;
    const int base = t * 4;
    int v0 = (base + 0 < nb) ? bsum[base + 0] : 0;
    int v1 = (base + 1 < nb) ? bsum[base + 1] : 0;
    int v2 = (base + 2 < nb) ? bsum[base + 2] : 0;
    int v3 = (base + 3 < nb) ? bsum[base + 3] : 0;
    int local = v0 + v1 + v2 + v3;
    ts[t] = local;
    __syncthreads();
    for (int off = 1; off < 256; off <<= 1) {
        int x = (t >= off) ? ts[t - off] : 0;
        __syncthreads();
        ts[t] += x;
        __syncthreads();
    }
    int ex = ts[t] - local;
    if (base + 0 < nb) bsum[base + 0] = ex;
    if (base + 1 < nb) bsum[base + 1] = ex + v0;
    if (base + 2 < nb) bsum[base + 2] = ex + v0 + v1;
    if (base + 3 < nb) bsum[base + 3] = ex + v0 + v1 + v2;
}

__global__ void k_scan3(int* __restrict__ rs, const int* __restrict__ bsum, int n) {
    int i = blockIdx.x * blockDim.x + threadIdx.x;
    if (i < n) rs[i] += bsum[i >> 10];
}

// fill: bump rs (becomes end-offsets; start(w) = rs[w-1])
__global__ void k_fill_ub(const int* __restrict__ us, const int* __restrict__ ud,
                          int* __restrict__ rs, int* __restrict__ eidx) {
    int e = blockIdx.x * blockDim.x + threadIdx.x;
    if (e < NE_UB) {
        int u = us[e];
        int b = U_N + ud[e];
        int pu = atomicAdd(&rs[u], 1);
        eidx[pu] = b;
        int pb = atomicAdd(&rs[b], 1);
        eidx[pb] = u;
    }
}

__global__ void k_fill_bb(const int* __restrict__ bs, const int* __restrict__ bd,
                          int* __restrict__ rs, int* __restrict__ eidx) {
    int e = blockIdx.x * blockDim.x + threadIdx.x;
    if (e < NE_BB) {
        int p = atomicAdd(&rs[bd[e]], 1);
        eidx[p] = bs[e];
    }
}

// ---------------- pull-mode propagation (no feature atomics) ----------------

// one wave per node; lane holds cols (2l, 2l+1).
// FINAL=false: xout[w] = sum_nb xin[nb]*dinv[nb]*dinv[w]
// FINAL=true : xout[w] = (x0[w] + xin[w] + sum_nb ...)/3   (x0 aliases xout row-wise: safe)
template<bool FINAL>
__global__ void k_gather_ub(const int* __restrict__ rs, const int* __restrict__ eidx,
                            const float* __restrict__ dinv,
                            const float* __restrict__ xin, float* xout,
                            const float* x0) {
    int w    = (blockIdx.x * blockDim.x + threadIdx.x) >> 6;
    int lane = threadIdx.x & 63;
    if (w >= N_TOT) return;
    int s = (w == 0) ? 0 : rs[w - 1];
    int e = rs[w];
    s = __builtin_amdgcn_readfirstlane(s);
    e = __builtin_amdgcn_readfirstlane(e);
    float nd = dinv[w];
    float2 acc = make_float2(0.0f, 0.0f);
    for (int j = s; j < e; ++j) {
        int nb = eidx[j];
        float wgt = nd * dinv[nb];
        float2 v = ((const float2*)(xin + (size_t)nb * HD))[lane];
        acc.x = fmaf(v.x, wgt, acc.x);
        acc.y = fmaf(v.y, wgt, acc.y);
    }
    if (FINAL) {
        float2 a = ((const float2*)(x0 + (size_t)w * HD))[lane];
        float2 b = ((const float2*)(xin + (size_t)w * HD))[lane];
        acc.x = (acc.x + a.x + b.x) * (1.0f / 3.0f);
        acc.y = (acc.y + a.y + b.y) * (1.0f / 3.0f);
    }
    ((float2*)(xout + (size_t)w * HD))[lane] = acc;
}

// one wave per book: agg[w] = (sum_nb h[nb]) / max(deg,1)
__global__ void k_gather_bb(const int* __restrict__ rs, const int* __restrict__ eidx,
                            const float* __restrict__ h, float* __restrict__ agg) {
    int w    = (blockIdx.x * blockDim.x + threadIdx.x) >> 6;
    int lane = threadIdx.x & 63;
    if (w >= B_N) return;
    int s = (w == 0) ? 0 : rs[w - 1];
    int e = rs[w];
    s = __builtin_amdgcn_readfirstlane(s);
    e = __builtin_amdgcn_readfirstlane(e);
    float2 acc = make_float2(0.0f, 0.0f);
    for (int j = s; j < e; ++j) {
        int nb = eidx[j];
        float2 v = ((const float2*)(h + (size_t)nb * HD))[lane];
        acc.x += v.x;
        acc.y += v.y;
    }
    float inv = 1.0f / fmaxf((float)(e - s), 1.0f);
    acc.x *= inv;
    acc.y *= inv;
    ((float2*)(agg + (size_t)w * HD))[lane] = acc;
}

// hout[r,c] = relu( agg[r] @ Wl + bl + h[r] @ Wr )   (agg pre-divided)
__global__ void k_glayer(const float* __restrict__ agg, const float* __restrict__ h,
                         const float* __restrict__ Wl, const float* __restrict__ bl,
                         const float* __restrict__ Wr, float* __restrict__ hout) {
    __shared__ float sa[8][HD];
    __shared__ float sh[8][HD];
    const int c  = threadIdx.x;
    const int r0 = blockIdx.x * 8;
#pragma unroll
    for (int i = 0; i < 8; i++) {
        int r = r0 + i;
        sa[i][c] = (r < B_N) ? agg[(size_t)r * HD + c] : 0.0f;
        sh[i][c] = (r < B_N) ? h[(size_t)r * HD + c] : 0.0f;
    }
    __syncthreads();
    float acc[8];
#pragma unroll
    for (int i = 0; i < 8; i++) acc[i] = 0.0f;
    for (int k = 0; k < HD; k++) {
        float wl = Wl[k * HD + c];
        float wr = Wr[k * HD + c];
#pragma unroll
        for (int i = 0; i < 8; i++) {
            acc[i] = fmaf(sa[i][k], wl, acc[i]);
            acc[i] = fmaf(sh[i][k], wr, acc[i]);
        }
    }
    float bv = bl[c];
#pragma unroll
    for (int i = 0; i < 8; i++) {
        int r = r0 + i;
        if (r < B_N) hout[(size_t)r * HD + c] = fmaxf(acc[i] + bv, 0.0f);
    }
}

// attention fusion head, 4 rows per 128-thread block (2 waves)
__global__ void k_fuse(const float* __restrict__ collab, const float* __restrict__ content,
                       const float* __restrict__ Wf1, const float* __restrict__ bf1v,
                       const float* __restrict__ Wf2, const float* __restrict__ bf2v,
                       float* __restrict__ fused) {
    const int R = 4;
    __shared__ float sc[R][HD];
    __shared__ float sh[R][HD];
    __shared__ float part[2][R][2];
    __shared__ float attn[R][2];
    const int c  = threadIdx.x;
    const int r0 = blockIdx.x * R;
#pragma unroll
    for (int i = 0; i < R; i++) {
        int r = r0 + i;
        sc[i][c] = (r < B_N) ? collab[(size_t)r * HD + c] : 0.0f;
        sh[i][c] = (r < B_N) ? content[(size_t)r * HD + c] : 0.0f;
    }
    __syncthreads();
    float t[R];
#pragma unroll
    for (int i = 0; i < R; i++) t[i] = 0.0f;
    for (int k = 0; k < HD; k++) {
        float w = Wf1[k * HD + c];
#pragma unroll
        for (int i = 0; i < R; i++) t[i] = fmaf(sc[i][k], w, t[i]);
    }
    for (int k = 0; k < HD; k++) {
        float w = Wf1[(size_t)(HD + k) * HD + c];
#pragma unroll
        for (int i = 0; i < R; i++) t[i] = fmaf(sh[i][k], w, t[i]);
    }
    float b1  = bf1v[c];
    float w20 = Wf2[c * 2 + 0];
    float w21 = Wf2[c * 2 + 1];
    float p0[R], p1[R];
#pragma unroll
    for (int i = 0; i < R; i++) {
        float tv = fmaxf(t[i] + b1, 0.0f);
        p0[i] = tv * w20;
        p1[i] = tv * w21;
    }
#pragma unroll
    for (int i = 0; i < R; i++) {
        for (int off = 32; off > 0; off >>= 1) {
            p0[i] += __shfl_down(p0[i], off, 64);
            p1[i] += __shfl_down(p1[i], off, 64);
        }
    }
    int wv   = threadIdx.x >> 6;
    int lane = threadIdx.x & 63;
    if (lane == 0) {
#pragma unroll
        for (int i = 0; i < R; i++) { part[wv][i][0] = p0[i]; part[wv][i][1] = p1[i]; }
    }
    __syncthreads();
    if (threadIdx.x < R) {
        int i = threadIdx.x;
        float s0 = part[0][i][0] + part[1][i][0] + bf2v[0];
        float s1 = part[0][i][1] + part[1][i][1] + bf2v[1];
        float m  = fmaxf(s0, s1);
        float e0 = expf(s0 - m), e1 = expf(s1 - m);
        float inv = 1.0f / (e0 + e1);
        attn[i][0] = e0 * inv;
        attn[i][1] = e1 * inv;
    }
    __syncthreads();
#pragma unroll
    for (int i = 0; i < R; i++) {
        int r = r0 + i;
        if (r < B_N)
            fused[(size_t)r * HD + c] = attn[i][0] * sc[i][c] + attn[i][1] * sh[i][c];
    }
}

// one wave per prediction: dot(user_emb[pu], fused[pb]); OUTPUT IS F32
// (R3 passed writing f32 output via its f32 branch; R6's only delta was a
//  bf16 output write and it failed with the bf16-packed-read signature.)
__global__ void k_score(const int* __restrict__ pu, const int* __restrict__ pb,
                        const float* __restrict__ uemb, const float* __restrict__ fused,
                        float* __restrict__ out) {
    int wid  = (blockIdx.x * blockDim.x + threadIdx.x) >> 6;
    int lane = threadIdx.x & 63;
    if (wid >= NP) return;
    int u = pu[wid];
    int b = pb[wid];
    float2 a = ((const float2*)(uemb + (size_t)u * HD))[lane];
    float2 f = ((const float2*)(fused + (size_t)b * HD))[lane];
    float s = a.x * f.x + a.y * f.y;
    for (int off = 32; off > 0; off >>= 1) s += __shfl_down(s, off, 64);
    if (lane == 0) out[wid] = s;
}

extern "C" void kernel_launch(void* const* d_in, const int* in_sizes, int n_in,
                              void* d_out, int out_size, void* d_ws, size_t ws_size,
                              hipStream_t stream) {
    // INPUTS F32, OUTPUT F32 (established R3/R6 A/B evidence).
    const float* user_x = (const float*)d_in[0];
    const float* book_x = (const float*)d_in[1];
    const int*   ub_src = (const int*)d_in[2];
    const int*   ub_dst = (const int*)d_in[3];
    const int*   bb_src = (const int*)d_in[4];
    const int*   bb_dst = (const int*)d_in[5];
    const int*   pred_u = (const int*)d_in[6];
    const int*   pred_b = (const int*)d_in[7];
    const float* Wu   = (const float*)d_in[8];
    const float* bu   = (const float*)d_in[9];
    const float* Wub  = (const float*)d_in[10];
    const float* bub  = (const float*)d_in[11];
    const float* Wbb  = (const float*)d_in[12];
    const float* bbb  = (const float*)d_in[13];
    const float* Wl1  = (const float*)d_in[14];
    const float* bl1  = (const float*)d_in[15];
    const float* Wr1  = (const float*)d_in[16];
    const float* Wl2  = (const float*)d_in[17];
    const float* bl2  = (const float*)d_in[18];
    const float* Wr2  = (const float*)d_in[19];
    const float* Wf1  = (const float*)d_in[20];
    const float* bf1v = (const float*)d_in[21];
    const float* Wf2  = (const float*)d_in[22];
    const float* bf2v = (const float*)d_in[23];
    float* out = (float*)d_out;

    // ---- workspace layout (4-byte words), total 40.56M words = 162.24 MB ----
    // (R4 executed past this exact guard -> ws_size >= 162.24 MB is PROVEN.)
    // aux   [0,560000): dinv|cnt_ub|rs_ub|cnt_bb|rs_bb|bsum
    // eidx  [560000, 2160000): ub CSR; bb CSR aliased after round 2
    // XBUF  [2160000, 21360000): N*H f32 (x1); content tiles hA/agg/hB after
    // ACC   [21360000, 40560000): N*H f32 (x0 -> xf)
    float* ws = (float*)d_ws;
    const size_t NH = (size_t)N_TOT * HD;
    const size_t need = (560000 + (size_t)2 * NE_UB + 2 * NH) * sizeof(float);
    if (ws_size < need) return;  // would show absmax == max|ref|, not NaN

    float* dinv    = ws;
    int*   cnt_ub  = (int*)(ws + 150000);
    int*   rs_ub   = (int*)(ws + 300000);
    int*   cnt_bb  = (int*)(ws + 450000);
    int*   rs_bb   = (int*)(ws + 500000);
    int*   bsum    = (int*)(ws + 550000);
    int*   eidx_ub = (int*)(ws + 560000);        // 2*NE_UB ints
    int*   eidx_bb = eidx_ub;                    // live only after round 2
    float* XBUF  = ws + 2160000;                 // N*H f32
    float* ACC   = XBUF + NH;                    // N*H f32
    float* hA    = XBUF;                         // B*H
    float* agg   = XBUF + (size_t)B_N * HD;      // B*H
    float* hB    = XBUF + 2 * (size_t)B_N * HD;  // B*H (3*B*H == N*H)
    float* fused = agg;                          // after layer 2

    // zero count arrays (ws poisoned 0xAA each launch); rs/bsum fully overwritten
    hipMemsetAsync(ws + 150000, 0, 350000 * sizeof(float), stream);

    // x0 = [user_x@Wu+bu ; book_x@Wub+bub] -> ACC
    k_init_gemm<DU><<<(U_N + 7) / 8, 128, 0, stream>>>(user_x, Wu, bu, ACC, U_N);
    k_init_gemm<DB><<<(B_N + 7) / 8, 128, 0, stream>>>(book_x, Wub, bub,
                                                       ACC + (size_t)U_N * HD, B_N);

    // ---- CSR build (ub graph, bidirectional) ----
    k_cnt_ub<<<(NE_UB + 255) / 256, 256, 0, stream>>>(ub_src, ub_dst, cnt_ub);
    k_cnt_bb<<<(NE_BB + 255) / 256, 256, 0, stream>>>(bb_dst, cnt_bb);
    k_dinv<<<(N_TOT + 255) / 256, 256, 0, stream>>>(cnt_ub, dinv);
    {
        int nb = (N_TOT + 1023) / 1024;
        k_scan1<<<nb, 256, 0, stream>>>(cnt_ub, rs_ub, bsum, N_TOT);
        k_scan2<<<1, 256, 0, stream>>>(bsum, nb);
        k_scan3<<<(N_TOT + 255) / 256, 256, 0, stream>>>(rs_ub, bsum, N_TOT);
    }
    k_fill_ub<<<(NE_UB + 255) / 256, 256, 0, stream>>>(ub_src, ub_dst, rs_ub, eidx_ub);

    // ---- LightGCN propagation, pull mode ----
    // round 1: x1 = P x0   (ACC -> XBUF)
    k_gather_ub<false><<<(N_TOT + 3) / 4, 256, 0, stream>>>(
        rs_ub, eidx_ub, dinv, ACC, XBUF, nullptr);
    // round 2 fused: ACC = (x0 + x1 + P x1)/3   (row-local in-place on ACC)
    k_gather_ub<true><<<(N_TOT + 3) / 4, 256, 0, stream>>>(
        rs_ub, eidx_ub, dinv, XBUF, ACC, ACC);

    // ---- CSR build (bb graph) — ub CSR dead, eidx region reused ----
    {
        int nb = (B_N + 1023) / 1024;
        k_scan1<<<nb, 256, 0, stream>>>(cnt_bb, rs_bb, bsum, B_N);
        k_scan2<<<1, 256, 0, stream>>>(bsum, nb);
        k_scan3<<<(B_N + 255) / 256, 256, 0, stream>>>(rs_bb, bsum, B_N);
    }
    k_fill_bb<<<(NE_BB + 255) / 256, 256, 0, stream>>>(bb_src, bb_dst, rs_bb, eidx_bb);

    // ---- content network (XBUF region now free: hA/agg/hB tiles) ----
    k_init_gemm<DB><<<(B_N + 7) / 8, 128, 0, stream>>>(book_x, Wbb, bbb, hA, B_N);
    k_gather_bb<<<(B_N + 3) / 4, 256, 0, stream>>>(rs_bb, eidx_bb, hA, agg);
    k_glayer<<<(B_N + 7) / 8, 128, 0, stream>>>(agg, hA, Wl1, bl1, Wr1, hB);
    k_gather_bb<<<(B_N + 3) / 4, 256, 0, stream>>>(rs_bb, eidx_bb, hB, agg);
    k_glayer<<<(B_N + 7) / 8, 128, 0, stream>>>(agg, hB, Wl2, bl2, Wr2, hA);

    // ---- fusion + scores ----
    k_fuse<<<(B_N + 3) / 4, 128, 0, stream>>>(ACC + (size_t)U_N * HD, hA,
                                              Wf1, bf1v, Wf2, bf2v, fused);
    k_score<<<NP / 4, 256, 0, stream>>>(pred_u, pred_b, ACC, fused, out);
}

// Round 9
// 1218.876 us; speedup vs baseline: 3.6652x; 1.0624x over previous
//
#include <hip/hip_runtime.h>
#include <hip/hip_bf16.h>

typedef __hip_bfloat16 bf16;
typedef __hip_bfloat162 bf162;

#define U_N   100000
#define B_N   50000
#define N_TOT 150000
#define NE_UB 800000
#define NE_BB 600000
#define NP    400000
#define DU    64
#define DB    128
#define HD    128

__device__ __forceinline__ float b2f(bf16 v) { return __bfloat162float(v); }
__device__ __forceinline__ float2 ldb2(const bf16* row, int lane) {
    bf162 v = ((const bf162*)row)[lane];
    return make_float2(b2f(v.x), b2f(v.y));
}
__device__ __forceinline__ void stb2(bf16* row, int lane, float2 v) {
    bf162 o;
    o.x = __float2bfloat16(v.x);
    o.y = __float2bfloat16(v.y);
    ((bf162*)row)[lane] = o;
}

// ---------------- dense blocks (f32 compute; f32 and/or bf16 outputs) ----------------

template<int K>
__global__ void k_init_gemm(const float* __restrict__ x, const float* __restrict__ W,
                            const float* __restrict__ bias,
                            float* outf, bf16* out16, int nrows) {
    __shared__ float row[8][K];
    const int c  = threadIdx.x;
    const int r0 = blockIdx.x * 8;
    for (int i = threadIdx.x; i < 8 * K; i += 128) {
        int rr = i / K, kk = i % K;
        int r = r0 + rr;
        row[rr][kk] = (r < nrows) ? x[(size_t)r * K + kk] : 0.0f;
    }
    __syncthreads();
    float acc[8];
#pragma unroll
    for (int i = 0; i < 8; i++) acc[i] = 0.0f;
    for (int k = 0; k < K; k++) {
        float w = W[k * HD + c];
#pragma unroll
        for (int i = 0; i < 8; i++) acc[i] = fmaf(row[i][k], w, acc[i]);
    }
    float bv = bias[c];
#pragma unroll
    for (int i = 0; i < 8; i++) {
        int r = r0 + i;
        if (r < nrows) {
            float v = acc[i] + bv;
            if (outf)  outf[(size_t)r * HD + c] = v;
            if (out16) out16[(size_t)r * HD + c] = __float2bfloat16(v);
        }
    }
}

// ---------------- CSR build: count -> scan -> fill ----------------

__global__ void k_cnt_ub(const int* __restrict__ us, const int* __restrict__ ud,
                         int* __restrict__ cnt) {
    int e = blockIdx.x * blockDim.x + threadIdx.x;
    if (e < NE_UB) {
        atomicAdd(&cnt[us[e]], 1);
        atomicAdd(&cnt[U_N + ud[e]], 1);
    }
}

__global__ void k_cnt_bb(const int* __restrict__ bd, int* __restrict__ cnt) {
    int e = blockIdx.x * blockDim.x + threadIdx.x;
    if (e < NE_BB) atomicAdd(&cnt[bd[e]], 1);
}

__global__ void k_dinv(const int* __restrict__ cnt, float* __restrict__ dinv) {
    int i = blockIdx.x * blockDim.x + threadIdx.x;
    if (i < N_TOT) {
        int d = cnt[i];
        dinv[i] = (d > 0) ? 1.0f / sqrtf((float)d) : 0.0f;
    }
}

__global__ void k_scan1(const int* __restrict__ cnt, int* __restrict__ rs,
                        int* __restrict__ bsum, int n) {
    __shared__ int ts[256];
    const int t = threadIdx.x;
    const int base = blockIdx.x * 1024 + t * 4;
    int v0 = (base + 0 < n) ? cnt[base + 0] : 0;
    int v1 = (base + 1 < n) ? cnt[base + 1] : 0;
    int v2 = (base + 2 < n) ? cnt[base + 2] : 0;
    int v3 = (base + 3 < n) ? cnt[base + 3] : 0;
    int local = v0 + v1 + v2 + v3;
    ts[t] = local;
    __syncthreads();
    for (int off = 1; off < 256; off <<= 1) {
        int x = (t >= off) ? ts[t - off] : 0;
        __syncthreads();
        ts[t] += x;
        __syncthreads();
    }
    int ex = ts[t] - local;
    if (base + 0 < n) rs[base + 0] = ex;
    if (base + 1 < n) rs[base + 1] = ex + v0;
    if (base + 2 < n) rs[base + 2] = ex + v0 + v1;
    if (base + 3 < n) rs[base + 3] = ex + v0 + v1 + v2;
    if (t == 0) bsum[blockIdx.x] = ts[255];
}

__global__ void k_scan2(int* __restrict__ bsum, int nb) {
    __shared__ int ts[256];
    const int t = threadIdx.x;
    const int base = t * 4;
    int v0 = (base + 0 < nb) ? bsum[base + 0] : 0;
    int v1 = (base + 1 < nb) ? bsum[base + 1] : 0;
    int v2 = (base + 2 < nb) ? bsum[base + 2] : 0;
    int v3 = (base + 3 < nb) ? bsum[base + 3] : 0;
    int local = v0 + v1 + v2 + v3;
    ts[t] = local;
    __syncthreads();
    for (int off = 1; off < 256; off <<= 1) {
        int x = (t >= off) ? ts[t - off] : 0;
        __syncthreads();
        ts[t] += x;
        __syncthreads();
    }
    int ex = ts[t] - local;
    if (base + 0 < nb) bsum[base + 0] = ex;
    if (base + 1 < nb) bsum[base + 1] = ex + v0;
    if (base + 2 < nb) bsum[base + 2] = ex + v0 + v1;
    if (base + 3 < nb) bsum[base + 3] = ex + v0 + v1 + v2;
}

__global__ void k_scan3(int* __restrict__ rs, const int* __restrict__ bsum, int n) {
    int i = blockIdx.x * blockDim.x + threadIdx.x;
    if (i < n) rs[i] += bsum[i >> 10];
}

__global__ void k_fill_ub(const int* __restrict__ us, const int* __restrict__ ud,
                          int* __restrict__ rs, int* __restrict__ eidx) {
    int e = blockIdx.x * blockDim.x + threadIdx.x;
    if (e < NE_UB) {
        int u = us[e];
        int b = U_N + ud[e];
        int pu = atomicAdd(&rs[u], 1);
        eidx[pu] = b;
        int pb = atomicAdd(&rs[b], 1);
        eidx[pb] = u;
    }
}

__global__ void k_fill_bb(const int* __restrict__ bs, const int* __restrict__ bd,
                          int* __restrict__ rs, int* __restrict__ eidx) {
    int e = blockIdx.x * blockDim.x + threadIdx.x;
    if (e < NE_BB) {
        int p = atomicAdd(&rs[bd[e]], 1);
        eidx[p] = bs[e];
    }
}

// ---------------- pull-mode propagation (bf16 tables, f32 accumulate) ----------------

// round 1: x1[w] = sum_nb x0[nb]*dinv[nb]*dinv[w]
__global__ void k_gather1(const int* __restrict__ rs, const int* __restrict__ eidx,
                          const float* __restrict__ dinv,
                          const bf16* __restrict__ x016, bf16* __restrict__ x116) {
    int w    = (blockIdx.x * blockDim.x + threadIdx.x) >> 6;
    int lane = threadIdx.x & 63;
    if (w >= N_TOT) return;
    int s = (w == 0) ? 0 : rs[w - 1];
    int e = rs[w];
    s = __builtin_amdgcn_readfirstlane(s);
    e = __builtin_amdgcn_readfirstlane(e);
    float nd = dinv[w];
    float2 acc = make_float2(0.0f, 0.0f);
    for (int j = s; j < e; ++j) {
        int nb = eidx[j];
        float wgt = nd * dinv[nb];
        float2 v = ldb2(x016 + (size_t)nb * HD, lane);
        acc.x = fmaf(v.x, wgt, acc.x);
        acc.y = fmaf(v.y, wgt, acc.y);
    }
    stb2(x116 + (size_t)w * HD, lane, acc);
}

// round 2: xf[w] = (x0[w] + x1[w] + sum_nb x1[nb]*dinv[nb]*dinv[w]) / 3
__global__ void k_gather2(const int* __restrict__ rs, const int* __restrict__ eidx,
                          const float* __restrict__ dinv,
                          const bf16* __restrict__ x016, const bf16* __restrict__ x116,
                          bf16* __restrict__ xf16) {
    int w    = (blockIdx.x * blockDim.x + threadIdx.x) >> 6;
    int lane = threadIdx.x & 63;
    if (w >= N_TOT) return;
    int s = (w == 0) ? 0 : rs[w - 1];
    int e = rs[w];
    s = __builtin_amdgcn_readfirstlane(s);
    e = __builtin_amdgcn_readfirstlane(e);
    float nd = dinv[w];
    float2 acc = make_float2(0.0f, 0.0f);
    for (int j = s; j < e; ++j) {
        int nb = eidx[j];
        float wgt = nd * dinv[nb];
        float2 v = ldb2(x116 + (size_t)nb * HD, lane);
        acc.x = fmaf(v.x, wgt, acc.x);
        acc.y = fmaf(v.y, wgt, acc.y);
    }
    float2 a = ldb2(x016 + (size_t)w * HD, lane);
    float2 b = ldb2(x116 + (size_t)w * HD, lane);
    acc.x = (acc.x + a.x + b.x) * (1.0f / 3.0f);
    acc.y = (acc.y + a.y + b.y) * (1.0f / 3.0f);
    stb2(xf16 + (size_t)w * HD, lane, acc);
}

// agg[w] = (sum_nb h16[nb]) / max(deg,1)   (bf16 in, f32 out)
__global__ void k_gather_bb(const int* __restrict__ rs, const int* __restrict__ eidx,
                            const bf16* __restrict__ h16, float* __restrict__ agg) {
    int w    = (blockIdx.x * blockDim.x + threadIdx.x) >> 6;
    int lane = threadIdx.x & 63;
    if (w >= B_N) return;
    int s = (w == 0) ? 0 : rs[w - 1];
    int e = rs[w];
    s = __builtin_amdgcn_readfirstlane(s);
    e = __builtin_amdgcn_readfirstlane(e);
    float2 acc = make_float2(0.0f, 0.0f);
    for (int j = s; j < e; ++j) {
        int nb = eidx[j];
        float2 v = ldb2(h16 + (size_t)nb * HD, lane);
        acc.x += v.x;
        acc.y += v.y;
    }
    float inv = 1.0f / fmaxf((float)(e - s), 1.0f);
    acc.x *= inv;
    acc.y *= inv;
    ((float2*)(agg + (size_t)w * HD))[lane] = acc;
}

// hout = relu(agg@Wl + bl + h@Wr); in-place safe (block-row-local via LDS)
__global__ void k_glayer(const float* __restrict__ agg, const float* __restrict__ h,
                         const float* __restrict__ Wl, const float* __restrict__ bl,
                         const float* __restrict__ Wr,
                         float* outf, bf16* out16) {
    __shared__ float sa[8][HD];
    __shared__ float sh[8][HD];
    const int c  = threadIdx.x;
    const int r0 = blockIdx.x * 8;
#pragma unroll
    for (int i = 0; i < 8; i++) {
        int r = r0 + i;
        sa[i][c] = (r < B_N) ? agg[(size_t)r * HD + c] : 0.0f;
        sh[i][c] = (r < B_N) ? h[(size_t)r * HD + c] : 0.0f;
    }
    __syncthreads();
    float acc[8];
#pragma unroll
    for (int i = 0; i < 8; i++) acc[i] = 0.0f;
    for (int k = 0; k < HD; k++) {
        float wl = Wl[k * HD + c];
        float wr = Wr[k * HD + c];
#pragma unroll
        for (int i = 0; i < 8; i++) {
            acc[i] = fmaf(sa[i][k], wl, acc[i]);
            acc[i] = fmaf(sh[i][k], wr, acc[i]);
        }
    }
    float bv = bl[c];
#pragma unroll
    for (int i = 0; i < 8; i++) {
        int r = r0 + i;
        if (r < B_N) {
            float v = fmaxf(acc[i] + bv, 0.0f);
            if (outf)  outf[(size_t)r * HD + c] = v;
            if (out16) out16[(size_t)r * HD + c] = __float2bfloat16(v);
        }
    }
}

// attention fusion head, 4 rows per 128-thread block (2 waves); bf16 in/out
__global__ void k_fuse(const bf16* __restrict__ collab16, const bf16* __restrict__ content16,
                       const float* __restrict__ Wf1, const float* __restrict__ bf1v,
                       const float* __restrict__ Wf2, const float* __restrict__ bf2v,
                       bf16* __restrict__ fused16) {
    const int R = 4;
    __shared__ float sc[R][HD];
    __shared__ float sh[R][HD];
    __shared__ float part[2][R][2];
    __shared__ float attn[R][2];
    const int c  = threadIdx.x;
    const int r0 = blockIdx.x * R;
#pragma unroll
    for (int i = 0; i < R; i++) {
        int r = r0 + i;
        sc[i][c] = (r < B_N) ? b2f(collab16[(size_t)r * HD + c]) : 0.0f;
        sh[i][c] = (r < B_N) ? b2f(content16[(size_t)r * HD + c]) : 0.0f;
    }
    __syncthreads();
    float t[R];
#pragma unroll
    for (int i = 0; i < R; i++) t[i] = 0.0f;
    for (int k = 0; k < HD; k++) {
        float w = Wf1[k * HD + c];
#pragma unroll
        for (int i = 0; i < R; i++) t[i] = fmaf(sc[i][k], w, t[i]);
    }
    for (int k = 0; k < HD; k++) {
        float w = Wf1[(size_t)(HD + k) * HD + c];
#pragma unroll
        for (int i = 0; i < R; i++) t[i] = fmaf(sh[i][k], w, t[i]);
    }
    float b1  = bf1v[c];
    float w20 = Wf2[c * 2 + 0];
    float w21 = Wf2[c * 2 + 1];
    float p0[R], p1[R];
#pragma unroll
    for (int i = 0; i < R; i++) {
        float tv = fmaxf(t[i] + b1, 0.0f);
        p0[i] = tv * w20;
        p1[i] = tv * w21;
    }
#pragma unroll
    for (int i = 0; i < R; i++) {
        for (int off = 32; off > 0; off >>= 1) {
            p0[i] += __shfl_down(p0[i], off, 64);
            p1[i] += __shfl_down(p1[i], off, 64);
        }
    }
    int wv   = threadIdx.x >> 6;
    int lane = threadIdx.x & 63;
    if (lane == 0) {
#pragma unroll
        for (int i = 0; i < R; i++) { part[wv][i][0] = p0[i]; part[wv][i][1] = p1[i]; }
    }
    __syncthreads();
    if (threadIdx.x < R) {
        int i = threadIdx.x;
        float s0 = part[0][i][0] + part[1][i][0] + bf2v[0];
        float s1 = part[0][i][1] + part[1][i][1] + bf2v[1];
        float m  = fmaxf(s0, s1);
        float e0 = expf(s0 - m), e1 = expf(s1 - m);
        float inv = 1.0f / (e0 + e1);
        attn[i][0] = e0 * inv;
        attn[i][1] = e1 * inv;
    }
    __syncthreads();
#pragma unroll
    for (int i = 0; i < R; i++) {
        int r = r0 + i;
        if (r < B_N) {
            float v = attn[i][0] * sc[i][c] + attn[i][1] * sh[i][c];
            fused16[(size_t)r * HD + c] = __float2bfloat16(v);
        }
    }
}

// one wave per prediction: dot(uemb16[pu], fused16[pb]); f32 out
__global__ void k_score(const int* __restrict__ pu, const int* __restrict__ pb,
                        const bf16* __restrict__ uemb16, const bf16* __restrict__ fused16,
                        float* __restrict__ out) {
    int wid  = (blockIdx.x * blockDim.x + threadIdx.x) >> 6;
    int lane = threadIdx.x & 63;
    if (wid >= NP) return;
    int u = pu[wid];
    int b = pb[wid];
    float2 a = ldb2(uemb16 + (size_t)u * HD, lane);
    float2 f = ldb2(fused16 + (size_t)b * HD, lane);
    float s = a.x * f.x + a.y * f.y;
    for (int off = 32; off > 0; off >>= 1) s += __shfl_down(s, off, 64);
    if (lane == 0) out[wid] = s;
}

extern "C" void kernel_launch(void* const* d_in, const int* in_sizes, int n_in,
                              void* d_out, int out_size, void* d_ws, size_t ws_size,
                              hipStream_t stream) {
    const float* user_x = (const float*)d_in[0];
    const float* book_x = (const float*)d_in[1];
    const int*   ub_src = (const int*)d_in[2];
    const int*   ub_dst = (const int*)d_in[3];
    const int*   bb_src = (const int*)d_in[4];
    const int*   bb_dst = (const int*)d_in[5];
    const int*   pred_u = (const int*)d_in[6];
    const int*   pred_b = (const int*)d_in[7];
    const float* Wu   = (const float*)d_in[8];
    const float* bu   = (const float*)d_in[9];
    const float* Wub  = (const float*)d_in[10];
    const float* bub  = (const float*)d_in[11];
    const float* Wbb  = (const float*)d_in[12];
    const float* bbb  = (const float*)d_in[13];
    const float* Wl1  = (const float*)d_in[14];
    const float* bl1  = (const float*)d_in[15];
    const float* Wr1  = (const float*)d_in[16];
    const float* Wl2  = (const float*)d_in[17];
    const float* bl2  = (const float*)d_in[18];
    const float* Wr2  = (const float*)d_in[19];
    const float* Wf1  = (const float*)d_in[20];
    const float* bf1v = (const float*)d_in[21];
    const float* Wf2  = (const float*)d_in[22];
    const float* bf2v = (const float*)d_in[23];
    float* out = (float*)d_out;

    // ---- workspace layout (4-byte words), total 30.96M words = 123.84 MB ----
    // All extents derived explicitly (R8 failed on a mis-sized mirror):
    //   N*H bf16 = 19.2M elems = 9.6M words ; B*H bf16 = 3.2M words ;
    //   B*H f32 = 6.4M words ; U*H bf16 = 6.4M words.
    // [0,       560000)   aux: dinv|cnt_ub|rs_ub|cnt_bb|rs_bb|bsum
    // [560000, 2160000)   eidx (ub CSR 1.6M; bb CSR 600k aliased later)
    // [2160000,11760000)  X016  bf16 N*H   | content: hf f32 [2160000,8560000)
    //                                      |          h16 bf16 [8560000,11760000)
    // [11760000,21360000) X1_16 bf16 N*H   | content: aggf f32 [11760000,18160000)
    //                                      |          fused16 [11760000,14960000) after aggf dies
    // [21360000,30960000) XF16  bf16 N*H   (uemb = rows 0..U, collab = rows U..N)
    float* ws = (float*)d_ws;
    const size_t need = 30960000ull * sizeof(float);
    if (ws_size < need) return;  // signature: absmax == max|ref|, not NaN

    float* dinv    = ws;
    int*   cnt_ub  = (int*)(ws + 150000);
    int*   rs_ub   = (int*)(ws + 300000);
    int*   cnt_bb  = (int*)(ws + 450000);
    int*   rs_bb   = (int*)(ws + 500000);
    int*   bsum    = (int*)(ws + 550000);
    int*   eidx    = (int*)(ws + 560000);
    bf16*  X016    = (bf16*)(ws + 2160000);      // [2160000, 11760000)
    bf16*  X1_16   = (bf16*)(ws + 11760000);     // [11760000, 21360000)
    bf16*  XF16    = (bf16*)(ws + 21360000);     // [21360000, 30960000)
    // content-phase aliases (X016/X1_16 dead after k_gather2)
    float* hf        = ws + 2160000;             // [2160000, 8560000)
    bf16*  h16       = (bf16*)(ws + 8560000);    // [8560000, 11760000)
    float* aggf      = ws + 11760000;            // [11760000, 18160000)
    bf16*  content16 = h16;                      // in-place over h2_16 (dead)
    bf16*  fused16   = (bf16*)(ws + 11760000);   // aggf region, dead at fuse time
    bf16*  uemb16    = XF16;
    bf16*  collab16  = XF16 + (size_t)U_N * HD;

    hipMemsetAsync(ws + 150000, 0, 350000 * sizeof(float), stream);

    // x0 -> X016 (bf16 only; f32 copy not needed downstream)
    k_init_gemm<DU><<<(U_N + 7) / 8, 128, 0, stream>>>(
        user_x, Wu, bu, (float*)nullptr, X016, U_N);
    k_init_gemm<DB><<<(B_N + 7) / 8, 128, 0, stream>>>(
        book_x, Wub, bub, (float*)nullptr, X016 + (size_t)U_N * HD, B_N);

    // ---- CSR build (ub graph, bidirectional) ----
    k_cnt_ub<<<(NE_UB + 255) / 256, 256, 0, stream>>>(ub_src, ub_dst, cnt_ub);
    k_cnt_bb<<<(NE_BB + 255) / 256, 256, 0, stream>>>(bb_dst, cnt_bb);
    k_dinv<<<(N_TOT + 255) / 256, 256, 0, stream>>>(cnt_ub, dinv);
    {
        int nb = (N_TOT + 1023) / 1024;
        k_scan1<<<nb, 256, 0, stream>>>(cnt_ub, rs_ub, bsum, N_TOT);
        k_scan2<<<1, 256, 0, stream>>>(bsum, nb);
        k_scan3<<<(N_TOT + 255) / 256, 256, 0, stream>>>(rs_ub, bsum, N_TOT);
    }
    k_fill_ub<<<(NE_UB + 255) / 256, 256, 0, stream>>>(ub_src, ub_dst, rs_ub, eidx);

    // ---- LightGCN propagation ----
    k_gather1<<<(N_TOT + 3) / 4, 256, 0, stream>>>(rs_ub, eidx, dinv, X016, X1_16);
    k_gather2<<<(N_TOT + 3) / 4, 256, 0, stream>>>(rs_ub, eidx, dinv, X016, X1_16, XF16);

    // ---- CSR build (bb graph) — ub CSR dead ----
    {
        int nb = (B_N + 1023) / 1024;
        k_scan1<<<nb, 256, 0, stream>>>(cnt_bb, rs_bb, bsum, B_N);
        k_scan2<<<1, 256, 0, stream>>>(bsum, nb);
        k_scan3<<<(B_N + 255) / 256, 256, 0, stream>>>(rs_bb, bsum, B_N);
    }
    k_fill_bb<<<(NE_BB + 255) / 256, 256, 0, stream>>>(bb_src, bb_dst, rs_bb, eidx);

    // ---- content network (X016/X1_16 region reused; in-place glayers) ----
    k_init_gemm<DB><<<(B_N + 7) / 8, 128, 0, stream>>>(book_x, Wbb, bbb, hf, h16, B_N);
    k_gather_bb<<<(B_N + 3) / 4, 256, 0, stream>>>(rs_bb, eidx, h16, aggf);
    // h2 = relu(aggf@Wl1 + bl1 + hf@Wr1) -> overwrite hf (f32) + h16 (bf16)
    k_glayer<<<(B_N + 7) / 8, 128, 0, stream>>>(aggf, hf, Wl1, bl1, Wr1, hf, h16);
    k_gather_bb<<<(B_N + 3) / 4, 256, 0, stream>>>(rs_bb, eidx, h16, aggf);
    // content = relu(aggf@Wl2 + bl2 + hf@Wr2) -> bf16 only, over h16 (dead)
    k_glayer<<<(B_N + 7) / 8, 128, 0, stream>>>(aggf, hf, Wl2, bl2, Wr2,
                                                (float*)nullptr, content16);

    // ---- fusion + scores ----
    k_fuse<<<(B_N + 3) / 4, 128, 0, stream>>>(collab16, content16,
                                              Wf1, bf1v, Wf2, bf2v, fused16);
    k_score<<<NP / 4, 256, 0, stream>>>(pred_u, pred_b, uemb16, fused16, out);
}